// Round 6
// baseline (196.041 us; speedup 1.0000x reference)
//
#include <hip/hip_runtime.h>
#include <hip/hip_bf16.h>
#include <stdint.h>

typedef __bf16 bf16;
typedef __attribute__((ext_vector_type(8))) __bf16 bf16x8;
typedef __attribute__((ext_vector_type(4))) __bf16 bf16x4;
typedef __attribute__((ext_vector_type(4))) float f32x4;
typedef __attribute__((ext_vector_type(16))) float f32x16;

#define AS1 __attribute__((address_space(1)))
#define AS3 __attribute__((address_space(3)))

__device__ __forceinline__ void async16(const void* g, void* l) {
  __builtin_amdgcn_global_load_lds((AS1 uint32_t*)(g), (AS3 uint32_t*)(l), 16, 0, 0);
}

__device__ __forceinline__ f32x4 mfma_bf16(bf16x8 a, bf16x8 b, f32x4 c) {
  return __builtin_amdgcn_mfma_f32_16x16x32_bf16(a, b, c, 0, 0, 0);
}

__device__ __forceinline__ f32x16 mfma32(bf16x8 a, bf16x8 b, f32x16 c) {
  return __builtin_amdgcn_mfma_f32_32x32x16_bf16(a, b, c, 0, 0, 0);
}

__device__ __forceinline__ uint32_t pack2_bf16(float a, float b) {
  union { __hip_bfloat162 h2; uint32_t u; } u;
  u.h2 = __float22bfloat162_rn(float2{a, b});  // packed cvt: x=low, y=high
  return u.u;
}

// ---------------------------------------------------------------- fused casts
__global__ __launch_bounds__(256) void cast_all_kernel(
    const float* __restrict__ x, const float* __restrict__ w1,
    const float* __restrict__ w2, bf16* __restrict__ xb,
    bf16* __restrict__ w1b, bf16* __restrict__ w2b) {
  const int bid = blockIdx.x;
  const float* src;
  bf16* dst;
  int base;
  if (bid < 4096) { src = x;  dst = xb;  base = bid; }
  else if (bid < 7168) { src = w1; dst = w1b; base = bid - 4096; }
  else { src = w2; dst = w2b; base = bid - 7168; }
  const int i = (base * 256 + threadIdx.x) * 4;
  const float4 v = *(const float4*)(src + i);
  bf16x4 o;
  o[0] = (bf16)v.x; o[1] = (bf16)v.y; o[2] = (bf16)v.z; o[3] = (bf16)v.w;
  *(bf16x4*)(dst + i) = o;
}

// ---------------------------------------------------------------- GEMM1: qkv = x @ qkv_w^T
// R0-proven 128x128 structure.
__global__ __launch_bounds__(256) void gemm_qkv_kernel(
    const bf16* __restrict__ A, const bf16* __restrict__ W,
    bf16* __restrict__ QK, bf16* __restrict__ VT) {
  constexpr int K = 1024;
  __shared__ __align__(16) bf16 sm[2 * 128 * 32];
  const int tid = threadIdx.x;
  const int w = tid >> 6, lane = tid & 63;
  const int m0 = blockIdx.x * 128, n0 = blockIdx.y * 128;
  const int wm = (w >> 1) * 64, wn = (w & 1) * 64;
  const int lrow = lane & 15, quad = lane >> 4;
  const int lk = quad * 8;
  f32x4 acc[4][4] = {};

  for (int k0 = 0; k0 < K; k0 += 32) {
#pragma unroll
    for (int i = 0; i < 4; ++i) {
      const int c = tid + 256 * i;
      const bf16* src = (c < 512)
          ? (A + (size_t)(m0 + (c >> 2)) * K + k0 + (c & 3) * 8)
          : (W + (size_t)(n0 + ((c - 512) >> 2)) * K + k0 + (c & 3) * 8);
      async16(src, sm + (w * 64 + i * 256) * 8);
    }
    __syncthreads();
    bf16x8 af[4], bfr[4];
#pragma unroll
    for (int mi = 0; mi < 4; ++mi)
      af[mi] = *(const bf16x8*)&sm[(wm + mi * 16 + lrow) * 32 + lk];
#pragma unroll
    for (int ni = 0; ni < 4; ++ni)
      bfr[ni] = *(const bf16x8*)&sm[128 * 32 + (wn + ni * 16 + lrow) * 32 + lk];
#pragma unroll
    for (int mi = 0; mi < 4; ++mi)
#pragma unroll
      for (int ni = 0; ni < 4; ++ni)
        acc[mi][ni] = mfma_bf16(af[mi], bfr[ni], acc[mi][ni]);
    __syncthreads();
  }

  // ---- epilogue: LDS transpose -> coalesced 16B global stores
  bf16* s2 = sm;  // [64][128]
  const bool isV = (n0 >= 2048);
  const int bb = m0 >> 11;
  const int mt = m0 & 2047;
  if (!isV) {
#pragma unroll
    for (int c = 0; c < 2; ++c) {
      if ((w >> 1) == c) {
#pragma unroll
        for (int mi = 0; mi < 4; ++mi)
#pragma unroll
          for (int ni = 0; ni < 4; ++ni) {
            const int nr = wn + ni * 16 + lrow;
#pragma unroll
            for (int r = 0; r < 4; ++r)
              s2[(mi * 16 + quad * 4 + r) * 128 + nr] = (bf16)acc[mi][ni][r];
          }
      }
      __syncthreads();
#pragma unroll
      for (int p = 0; p < 4; ++p) {
        const int row = p * 16 + (tid >> 4);
        const int colc = (tid & 15) * 8;
        const bf16x8 v = *(const bf16x8*)&s2[row * 128 + colc];
        *(bf16x8*)(QK + (size_t)(m0 + c * 64 + row) * 2048 + n0 + colc) = v;
      }
      __syncthreads();
    }
  } else {
#pragma unroll
    for (int c = 0; c < 2; ++c) {
      if ((w & 1) == c) {
#pragma unroll
        for (int mi = 0; mi < 4; ++mi)
#pragma unroll
          for (int ni = 0; ni < 4; ++ni) {
            const int nl = ni * 16 + lrow;
            bf16x4 pk4;
#pragma unroll
            for (int r = 0; r < 4; ++r) pk4[r] = (bf16)acc[mi][ni][r];
            *(bf16x4*)&s2[nl * 128 + wm + mi * 16 + quad * 4] = pk4;
          }
      }
      __syncthreads();
#pragma unroll
      for (int p = 0; p < 4; ++p) {
        const int row = p * 16 + (tid >> 4);
        const int colc = (tid & 15) * 8;
        const bf16x8 v = *(const bf16x8*)&s2[row * 128 + colc];
        const int vtrow = bb * 1024 + (n0 - 2048) + c * 64 + row;
        *(bf16x8*)(VT + (size_t)vtrow * 2048 + mt + colc) = v;
      }
      __syncthreads();
    }
  }
}

// ---------------------------------------------------------------- attention (flash, causal)
// R12: 32x32x16 MFMA structure. R11's pipe arithmetic: per-CU LDS reads were
// 256 KB/iter (3084 cyc @ 85B/cyc) vs MFMA floor 1400 cyc -> LDS-read bound.
// 32x32 fragments feed 2x FLOP per LDS byte: wave owns 32 q-rows, 4 waves =
// 128-row band, per-CU LDS reads halve to 128 KB/iter. Swapped QK^T
// (mfma(K,Q)) keeps q lane-local; P repacked to PV A-operand via
// cvt_pk + v_permlane32_swap (T12; crow=(r&3)+8(r>>2)+4h mapping); l via
// ones-B MFMA stays reg-aligned with accO (per-reg normalization, no
// shuffles). Balanced triangle (17 pair-iters/block), grid 256 = 1 block/CU,
// dbuf KV pair + counted vmcnt kept from R11.
__global__ __launch_bounds__(256) void attn_kernel(
    const bf16* __restrict__ QK, const bf16* __restrict__ VT,
    bf16* __restrict__ AO) {
  __shared__ __align__(16) bf16 sK[2][2][64 * 64];  // [buf][tile]: 32 KB
  __shared__ __align__(16) bf16 sV[2][2][64 * 64];  // [buf][tile]: 32 KB
  const int bid = blockIdx.x;
  const int bh = bid & 31;          // bid&7 == bh&7 -> XCD-local heads
  const int bp = bid >> 5;          // 0..7 band-pair index
  const int b = bh >> 4, hd = bh & 15;
  const int tid = threadIdx.x, w = tid >> 6, lane = tid & 63;
  const int ln31 = lane & 31, hf = lane >> 5;
  const bf16* Qb = QK + (size_t)b * 2048 * 2048 + hd * 64;
  const bf16* Kb = Qb + 1024;
  const bf16* Vb = VT + (size_t)bh * 64 * 2048;
  const float NEG_INF = -__builtin_inff();
  constexpr float QSCALE = 0.18033688011112042f;  // 0.125 * log2(e)
  const int n0 = 16 - bp;           // segment-0 pair count (band 15-bp)
  const int RH = (15 - bp) * 128 + w * 32;  // wave's 32-row slice, band H
  const int RL = bp * 128 + w * 32;         // band L

  // ones B-frag (bf16 1.0 = 0x3F80) for l = P . ones
  union { uint32_t u[4]; bf16x8 v; } ones;
  ones.u[0] = 0x3F803F80u; ones.u[1] = 0x3F803F80u;
  ones.u[2] = 0x3F803F80u; ones.u[3] = 0x3F803F80u;

  // Q B-frags (32x32x16: col=lane&31 -> q=R+ln31, k=d=8*hf+e per kstep),
  // pre-scaled, for both segments
  bf16x8 qfH[4], qfL[4];
#pragma unroll
  for (int ks = 0; ks < 4; ++ks) {
    bf16x8 v0 = *(const bf16x8*)(Qb + (size_t)(RH + ln31) * 2048 + ks * 16 + hf * 8);
    bf16x8 v1 = *(const bf16x8*)(Qb + (size_t)(RL + ln31) * 2048 + ks * 16 + hf * 8);
#pragma unroll
    for (int e = 0; e < 8; ++e) {
      v0[e] = (bf16)((float)v0[e] * QSCALE);
      v1[e] = (bf16)((float)v1[e] * QSCALE);
    }
    qfH[ks] = v0; qfL[ks] = v1;
  }

  // stage a pair of kv tiles into buffer c: K rows [s0,s0+128), V^T cols same
  // 256 threads x 8 async16 each (chunk-XOR swizzle on the global source)
  auto stage = [&](int s0, int c) {
    bf16* dK = &sK[c][0][0];
    bf16* dV = &sV[c][0][0];
#pragma unroll
    for (int i2 = 0; i2 < 4; ++i2) {
      const int L = tid + 256 * i2;         // 0..1023 chunks of 16B
      const int buf = L >> 9, Lr = L & 511;
      const int row = Lr >> 3;
      const int ch = (Lr & 7) ^ (row & 7);
      async16(Kb + (size_t)(s0 + buf * 64 + row) * 2048 + ch * 8, dK + L * 8);
    }
#pragma unroll
    for (int i2 = 0; i2 < 4; ++i2) {
      const int L = tid + 256 * i2;
      const int buf = L >> 9, Lr = L & 511;
      const int d = Lr >> 3;
      const int ch = (Lr & 7) ^ (d & 7);
      async16(Vb + (size_t)d * 2048 + s0 + buf * 64 + ch * 8, dV + L * 8);
    }
  };

  f32x16 accO0 = {}, accO1 = {};  // O[q][d]: dt0 = d 0..31, dt1 = d 32..63
  f32x16 accL = {};               // l[q] via ones-MFMA (cols all equal)

  // one 64-kv tile body for this wave's 32 q-rows
  auto body = [&](const bf16* kbuf, const bf16* vbuf, const bf16x8 (&qf)[4],
                  int kv0, int R, bool masked) {
    // QK^T: st[mt] = K[mt*32+ln31][:] . Q  (A row = lane&31, k = 8*hf+e)
    f32x16 st0 = {}, st1 = {};
#pragma unroll
    for (int ks = 0; ks < 4; ++ks) {
      const int ch = (((2 * ks + hf) ^ (ln31 & 7)) * 8);
      const bf16x8 kf0 = *(const bf16x8*)&kbuf[ln31 * 64 + ch];
      const bf16x8 kf1 = *(const bf16x8*)&kbuf[(32 + ln31) * 64 + ch];
      st0 = mfma32(kf0, qf[ks], st0);
      st1 = mfma32(kf1, qf[ks], st1);
    }
    // mask + p = exp2(st); C layout: col=q=R+ln31, row=crow(r,hf)
    const int q = R + ln31;
    float p0[16], p1[16];
#pragma unroll
    for (int r = 0; r < 16; ++r) {
      const int crow = (r & 3) + 8 * (r >> 2) + 4 * hf;
      float s0 = st0[r], s1 = st1[r];
      if (masked) {
        s0 = (kv0 + crow <= q) ? s0 : NEG_INF;
        s1 = (kv0 + 32 + crow <= q) ? s1 : NEG_INF;
      }
      p0[r] = __builtin_amdgcn_exp2f(s0);
      p1[r] = __builtin_amdgcn_exp2f(s1);
    }
    // repack P (rows kv split across lane halves) into PV A-frags:
    // pa[ks] lane needs kv = 16*ks + 8*hf + e for its q. cvt_pk pairs +
    // permlane32_swap: X'={X@h0|Y@h0}, Y'={X@h1|Y@h1}.
    bf16x8 pa[4];
#pragma unroll
    for (int mt = 0; mt < 2; ++mt) {
#pragma unroll
      for (int ksl = 0; ksl < 2; ++ksl) {
        const int bs = ksl * 8;
        uint32_t x0, y0, x1, y1;
        if (mt == 0) {
          x0 = pack2_bf16(p0[bs + 0], p0[bs + 1]);
          y0 = pack2_bf16(p0[bs + 4], p0[bs + 5]);
          x1 = pack2_bf16(p0[bs + 2], p0[bs + 3]);
          y1 = pack2_bf16(p0[bs + 6], p0[bs + 7]);
        } else {
          x0 = pack2_bf16(p1[bs + 0], p1[bs + 1]);
          y0 = pack2_bf16(p1[bs + 4], p1[bs + 5]);
          x1 = pack2_bf16(p1[bs + 2], p1[bs + 3]);
          y1 = pack2_bf16(p1[bs + 6], p1[bs + 7]);
        }
        asm volatile("v_permlane32_swap_b32 %0, %1" : "+v"(x0), "+v"(y0));
        asm volatile("v_permlane32_swap_b32 %0, %1" : "+v"(x1), "+v"(y1));
        union { uint32_t u[4]; bf16x8 v; } f;
        f.u[0] = x0; f.u[1] = x1; f.u[2] = y0; f.u[3] = y1;
        pa[mt * 2 + ksl] = f.v;
      }
    }
    // O += P.V (B: col=d=ln31(+32), k=kv); l += P.ones
#pragma unroll
    for (int ks = 0; ks < 4; ++ks) {
      const int ch = (((2 * ks + hf) ^ (ln31 & 7)) * 8);
      const bf16x8 vf0 = *(const bf16x8*)&vbuf[ln31 * 64 + ch];
      const bf16x8 vf1 = *(const bf16x8*)&vbuf[(32 + ln31) * 64 + ch];
      accO0 = mfma32(pa[ks], vf0, accO0);
      accO1 = mfma32(pa[ks], vf1, accO1);
      accL  = mfma32(pa[ks], ones.v, accL);
    }
  };

  auto writeout = [&](int R) {
    bf16* Ob = AO + (size_t)b * 2048 * 1024 + hd * 64;
#pragma unroll
    for (int r = 0; r < 16; ++r) {
      const int qr = R + (r & 3) + 8 * (r >> 2) + 4 * hf;
      const float inv = 1.0f / accL[r];
      Ob[(size_t)qr * 1024 + ln31]      = (bf16)(accO0[r] * inv);
      Ob[(size_t)qr * 1024 + 32 + ln31] = (bf16)(accO1[r] * inv);
    }
  };

  // ---- 17 identical pair-iterations per block, dbuf + counted vmcnt
  stage(0, 0);
  int cur = 0;
  for (int i = 0; i < 17; ++i) {
    if (i + 1 < 17) {
      const int nx = (i + 1 < n0) ? (i + 1) : (i + 1 - n0);
      stage(nx * 128, cur ^ 1);                         // next pair in flight
      asm volatile("s_waitcnt vmcnt(8)" ::: "memory");  // pair i landed
    } else {
      asm volatile("s_waitcnt vmcnt(0)" ::: "memory");  // final drain
    }
    __builtin_amdgcn_s_barrier();                       // pair i visible
    if (i < n0) {
      const int kv0 = i * 128;
      if (kv0 <= RH + 31)
        body(&sK[cur][0][0], &sV[cur][0][0], qfH, kv0, RH, kv0 + 63 > RH);
      if (kv0 + 64 <= RH + 31)
        body(&sK[cur][1][0], &sV[cur][1][0], qfH, kv0 + 64, RH, kv0 + 127 > RH);
      if (i == n0 - 1) {                                // segment 0 done
        writeout(RH);
        accO0 = f32x16{}; accO1 = f32x16{}; accL = f32x16{};
      }
    } else {
      const int kv0 = (i - n0) * 128;
      if (kv0 <= RL + 31)
        body(&sK[cur][0][0], &sV[cur][0][0], qfL, kv0, RL, kv0 + 63 > RL);
      if (kv0 + 64 <= RL + 31)
        body(&sK[cur][1][0], &sV[cur][1][0], qfL, kv0 + 64, RL, kv0 + 127 > RL);
    }
    __builtin_amdgcn_s_barrier();                       // reads done
    cur ^= 1;
  }
  writeout(RL);
}

// ---------------------------------------------------------------- GEMM2: y = attn_out @ out_w^T
__global__ __launch_bounds__(256) void gemm_out_kernel(
    const bf16* __restrict__ A, const bf16* __restrict__ W,
    float* __restrict__ C) {
  constexpr int K = 1024;
  __shared__ __align__(16) bf16 sm[2 * 128 * 32];
  const int tid = threadIdx.x;
  const int w = tid >> 6, lane = tid & 63;
  const int m0 = blockIdx.x * 128, n0 = blockIdx.y * 128;
  const int wm = (w >> 1) * 64, wn = (w & 1) * 64;
  const int lrow = lane & 15, lk = (lane >> 4) * 8;
  f32x4 acc[4][4] = {};

  for (int k0 = 0; k0 < K; k0 += 32) {
#pragma unroll
    for (int i = 0; i < 4; ++i) {
      const int c = tid + 256 * i;
      const bf16* src = (c < 512)
          ? (A + (size_t)(m0 + (c >> 2)) * K + k0 + (c & 3) * 8)
          : (W + (size_t)(n0 + ((c - 512) >> 2)) * K + k0 + (c & 3) * 8);
      async16(src, sm + (w * 64 + i * 256) * 8);
    }
    __syncthreads();
    bf16x8 af[4], bfr[4];
#pragma unroll
    for (int mi = 0; mi < 4; ++mi)
      af[mi] = *(const bf16x8*)&sm[(wm + mi * 16 + lrow) * 32 + lk];
#pragma unroll
    for (int ni = 0; ni < 4; ++ni)
      bfr[ni] = *(const bf16x8*)&sm[128 * 32 + (wn + ni * 16 + lrow) * 32 + lk];
#pragma unroll
    for (int mi = 0; mi < 4; ++mi)
#pragma unroll
      for (int ni = 0; ni < 4; ++ni)
        acc[mi][ni] = mfma_bf16(af[mi], bfr[ni], acc[mi][ni]);
    __syncthreads();
  }

#pragma unroll
  for (int mi = 0; mi < 4; ++mi)
#pragma unroll
    for (int ni = 0; ni < 4; ++ni) {
      const int n = n0 + wn + ni * 16 + lrow;
#pragma unroll
      for (int r = 0; r < 4; ++r) {
        const int m = m0 + wm + mi * 16 + (lane >> 4) * 4 + r;
        C[(size_t)m * 1024 + n] = acc[mi][ni][r];
      }
    }
}

// ---------------------------------------------------------------- launch
extern "C" void kernel_launch(void* const* d_in, const int* in_sizes, int n_in,
                              void* d_out, int out_size, void* d_ws, size_t ws_size,
                              hipStream_t stream) {
  const float* x     = (const float*)d_in[0];
  const float* qkv_w = (const float*)d_in[1];
  const float* out_w = (const float*)d_in[2];
  float* out = (float*)d_out;

  char* ws = (char*)d_ws;
  bf16* xb    = (bf16*)(ws);                      // 8 MB  [4096][1024]
  bf16* aob   = (bf16*)(ws);                      // 8 MB  alias (xb dead after gemm_qkv)
  bf16* wqkvb = (bf16*)(ws + 8u * 1024 * 1024);   // 6 MB  [3072][1024]
  bf16* wob   = (bf16*)(ws + 14u * 1024 * 1024);  // 2 MB  [1024][1024]
  bf16* qkb   = (bf16*)(ws + 16u * 1024 * 1024);  // 16 MB [4096][2048]
  bf16* vtb   = (bf16*)(ws + 32u * 1024 * 1024);  // 8 MB  [32*64][2048]

  cast_all_kernel<<<8192, 256, 0, stream>>>(x, qkv_w, out_w, xb, wqkvb, wob);
  gemm_qkv_kernel<<<dim3(32, 24), 256, 0, stream>>>(xb, wqkvb, qkb, vtb);
  attn_kernel<<<dim3(256), 256, 0, stream>>>(qkb, vtb, aob);
  gemm_out_kernel<<<dim3(32, 8), 256, 0, stream>>>(aob, wob, out);
}

// Round 7
// 176.343 us; speedup vs baseline: 1.1117x; 1.1117x over previous
//
#include <hip/hip_runtime.h>
#include <hip/hip_bf16.h>
#include <stdint.h>

typedef __bf16 bf16;
typedef __attribute__((ext_vector_type(8))) __bf16 bf16x8;
typedef __attribute__((ext_vector_type(4))) __bf16 bf16x4;
typedef __attribute__((ext_vector_type(4))) float f32x4;
typedef __attribute__((ext_vector_type(16))) float f32x16;

#define AS1 __attribute__((address_space(1)))
#define AS3 __attribute__((address_space(3)))

__device__ __forceinline__ void async16(const void* g, void* l) {
  __builtin_amdgcn_global_load_lds((AS1 uint32_t*)(g), (AS3 uint32_t*)(l), 16, 0, 0);
}

__device__ __forceinline__ f32x4 mfma_bf16(bf16x8 a, bf16x8 b, f32x4 c) {
  return __builtin_amdgcn_mfma_f32_16x16x32_bf16(a, b, c, 0, 0, 0);
}

__device__ __forceinline__ f32x16 mfma32(bf16x8 a, bf16x8 b, f32x16 c) {
  return __builtin_amdgcn_mfma_f32_32x32x16_bf16(a, b, c, 0, 0, 0);
}

__device__ __forceinline__ uint32_t pack2_bf16(float a, float b) {
  union { __hip_bfloat162 h2; uint32_t u; } u;
  u.h2 = __float22bfloat162_rn(float2{a, b});  // packed cvt: x=low, y=high
  return u.u;
}

// ---------------------------------------------------------------- fused casts
__global__ __launch_bounds__(256) void cast_all_kernel(
    const float* __restrict__ x, const float* __restrict__ w1,
    const float* __restrict__ w2, bf16* __restrict__ xb,
    bf16* __restrict__ w1b, bf16* __restrict__ w2b) {
  const int bid = blockIdx.x;
  const float* src;
  bf16* dst;
  int base;
  if (bid < 4096) { src = x;  dst = xb;  base = bid; }
  else if (bid < 7168) { src = w1; dst = w1b; base = bid - 4096; }
  else { src = w2; dst = w2b; base = bid - 7168; }
  const int i = (base * 256 + threadIdx.x) * 4;
  const float4 v = *(const float4*)(src + i);
  bf16x4 o;
  o[0] = (bf16)v.x; o[1] = (bf16)v.y; o[2] = (bf16)v.z; o[3] = (bf16)v.w;
  *(bf16x4*)(dst + i) = o;
}

// ---------------------------------------------------------------- GEMM1: qkv = x @ qkv_w^T
// R0-proven 128x128 structure.
__global__ __launch_bounds__(256) void gemm_qkv_kernel(
    const bf16* __restrict__ A, const bf16* __restrict__ W,
    bf16* __restrict__ QK, bf16* __restrict__ VT) {
  constexpr int K = 1024;
  __shared__ __align__(16) bf16 sm[2 * 128 * 32];
  const int tid = threadIdx.x;
  const int w = tid >> 6, lane = tid & 63;
  const int m0 = blockIdx.x * 128, n0 = blockIdx.y * 128;
  const int wm = (w >> 1) * 64, wn = (w & 1) * 64;
  const int lrow = lane & 15, quad = lane >> 4;
  const int lk = quad * 8;
  f32x4 acc[4][4] = {};

  for (int k0 = 0; k0 < K; k0 += 32) {
#pragma unroll
    for (int i = 0; i < 4; ++i) {
      const int c = tid + 256 * i;
      const bf16* src = (c < 512)
          ? (A + (size_t)(m0 + (c >> 2)) * K + k0 + (c & 3) * 8)
          : (W + (size_t)(n0 + ((c - 512) >> 2)) * K + k0 + (c & 3) * 8);
      async16(src, sm + (w * 64 + i * 256) * 8);
    }
    __syncthreads();
    bf16x8 af[4], bfr[4];
#pragma unroll
    for (int mi = 0; mi < 4; ++mi)
      af[mi] = *(const bf16x8*)&sm[(wm + mi * 16 + lrow) * 32 + lk];
#pragma unroll
    for (int ni = 0; ni < 4; ++ni)
      bfr[ni] = *(const bf16x8*)&sm[128 * 32 + (wn + ni * 16 + lrow) * 32 + lk];
#pragma unroll
    for (int mi = 0; mi < 4; ++mi)
#pragma unroll
      for (int ni = 0; ni < 4; ++ni)
        acc[mi][ni] = mfma_bf16(af[mi], bfr[ni], acc[mi][ni]);
    __syncthreads();
  }

  // ---- epilogue: LDS transpose -> coalesced 16B global stores
  bf16* s2 = sm;  // [64][128]
  const bool isV = (n0 >= 2048);
  const int bb = m0 >> 11;
  const int mt = m0 & 2047;
  if (!isV) {
#pragma unroll
    for (int c = 0; c < 2; ++c) {
      if ((w >> 1) == c) {
#pragma unroll
        for (int mi = 0; mi < 4; ++mi)
#pragma unroll
          for (int ni = 0; ni < 4; ++ni) {
            const int nr = wn + ni * 16 + lrow;
#pragma unroll
            for (int r = 0; r < 4; ++r)
              s2[(mi * 16 + quad * 4 + r) * 128 + nr] = (bf16)acc[mi][ni][r];
          }
      }
      __syncthreads();
#pragma unroll
      for (int p = 0; p < 4; ++p) {
        const int row = p * 16 + (tid >> 4);
        const int colc = (tid & 15) * 8;
        const bf16x8 v = *(const bf16x8*)&s2[row * 128 + colc];
        *(bf16x8*)(QK + (size_t)(m0 + c * 64 + row) * 2048 + n0 + colc) = v;
      }
      __syncthreads();
    }
  } else {
#pragma unroll
    for (int c = 0; c < 2; ++c) {
      if ((w & 1) == c) {
#pragma unroll
        for (int mi = 0; mi < 4; ++mi)
#pragma unroll
          for (int ni = 0; ni < 4; ++ni) {
            const int nl = ni * 16 + lrow;
            bf16x4 pk4;
#pragma unroll
            for (int r = 0; r < 4; ++r) pk4[r] = (bf16)acc[mi][ni][r];
            *(bf16x4*)&s2[nl * 128 + wm + mi * 16 + quad * 4] = pk4;
          }
      }
      __syncthreads();
#pragma unroll
      for (int p = 0; p < 4; ++p) {
        const int row = p * 16 + (tid >> 4);
        const int colc = (tid & 15) * 8;
        const bf16x8 v = *(const bf16x8*)&s2[row * 128 + colc];
        const int vtrow = bb * 1024 + (n0 - 2048) + c * 64 + row;
        *(bf16x8*)(VT + (size_t)vtrow * 2048 + mt + colc) = v;
      }
      __syncthreads();
    }
  }
}

// ---------------------------------------------------------------- attention (flash, causal)
// R13: 32x32x16 MFMA (R12's halved LDS-read volume) + 8 waves (R11's wave
// occupancy). R12 failed on launch shape: 256 threads = 1 wave/SIMD, zero TLP
// to hide the ds_read->QK->exp->repack->PV chain (occupancy 10%, 65us).
// Wave = (slice 0..3 = 32 q-rows, parity 0..1 = which 64-kv tile of the
// staged pair) -> all 8 waves run one body per iteration. Parity partials
// combined at segment ends via two-round LDS reduction (scratch = consumed
// cur buffers, disjoint from in-flight prefetch into cur^1). Balanced
// triangle (17 pair-iters), grid 256 = 1 block/CU, dbuf + counted vmcnt(4).
__global__ __launch_bounds__(512) void attn_kernel(
    const bf16* __restrict__ QK, const bf16* __restrict__ VT,
    bf16* __restrict__ AO) {
  __shared__ __align__(16) bf16 sK[2][2][64 * 64];  // [buf][tile]: 32 KB
  __shared__ __align__(16) bf16 sV[2][2][64 * 64];  // [buf][tile]: 32 KB
  const int bid = blockIdx.x;
  const int bh = bid & 31;          // bid&7 == bh&7 -> XCD-local heads
  const int bp = bid >> 5;          // 0..7 band-pair index
  const int b = bh >> 4, hd = bh & 15;
  const int tid = threadIdx.x, w = tid >> 6, lane = tid & 63;
  const int slice = w >> 1, parity = w & 1;
  const int ln31 = lane & 31, hf = lane >> 5;
  const bf16* Qb = QK + (size_t)b * 2048 * 2048 + hd * 64;
  const bf16* Kb = Qb + 1024;
  const bf16* Vb = VT + (size_t)bh * 64 * 2048;
  const float NEG_INF = -__builtin_inff();
  constexpr float QSCALE = 0.18033688011112042f;  // 0.125 * log2(e)
  const int n0 = 16 - bp;                   // segment-0 pair count
  const int RH = (15 - bp) * 128 + slice * 32;  // wave's 32 q-rows, band H
  const int RL = bp * 128 + slice * 32;         // band L

  // ones B-frag (bf16 1.0 = 0x3F80) for l = P . ones
  union { uint32_t u[4]; bf16x8 v; } ones;
  ones.u[0] = 0x3F803F80u; ones.u[1] = 0x3F803F80u;
  ones.u[2] = 0x3F803F80u; ones.u[3] = 0x3F803F80u;

  // Q B-frags (32x32x16: col=q=R+ln31, k=8*hf+e per kstep), pre-scaled
  bf16x8 qfH[4], qfL[4];
#pragma unroll
  for (int ks = 0; ks < 4; ++ks) {
    bf16x8 v0 = *(const bf16x8*)(Qb + (size_t)(RH + ln31) * 2048 + ks * 16 + hf * 8);
    bf16x8 v1 = *(const bf16x8*)(Qb + (size_t)(RL + ln31) * 2048 + ks * 16 + hf * 8);
#pragma unroll
    for (int e = 0; e < 8; ++e) {
      v0[e] = (bf16)((float)v0[e] * QSCALE);
      v1[e] = (bf16)((float)v1[e] * QSCALE);
    }
    qfH[ks] = v0; qfL[ks] = v1;
  }

  // stage a pair of kv tiles into buffer c: 512 threads x 2 chunks each for
  // K and V (chunk-XOR swizzle on the global source; LDS linear)
  auto stage = [&](int s0, int c) {
    bf16* dK = &sK[c][0][0];
    bf16* dV = &sV[c][0][0];
#pragma unroll
    for (int i2 = 0; i2 < 2; ++i2) {
      const int L = tid + 512 * i2;         // 0..1023 chunks of 16B
      const int buf = L >> 9, Lr = L & 511;
      const int row = Lr >> 3;
      const int ch = (Lr & 7) ^ (row & 7);
      async16(Kb + (size_t)(s0 + buf * 64 + row) * 2048 + ch * 8, dK + L * 8);
    }
#pragma unroll
    for (int i2 = 0; i2 < 2; ++i2) {
      const int L = tid + 512 * i2;
      const int buf = L >> 9, Lr = L & 511;
      const int d = Lr >> 3;
      const int ch = (Lr & 7) ^ (d & 7);
      async16(Vb + (size_t)d * 2048 + s0 + buf * 64 + ch * 8, dV + L * 8);
    }
  };

  f32x16 accO0 = {}, accO1 = {};  // O[q][d]: d 0..31 / 32..63 (parity partial)
  f32x16 accL = {};               // l[q] via ones-MFMA (parity partial)

  // one 64-kv tile body for this wave's 32 q-rows
  auto body = [&](const bf16* kbuf, const bf16* vbuf, const bf16x8* qf,
                  int kv0, int R, bool masked) {
    f32x16 st0 = {}, st1 = {};
#pragma unroll
    for (int ks = 0; ks < 4; ++ks) {
      const int ch = (((2 * ks + hf) ^ (ln31 & 7)) * 8);
      const bf16x8 kf0 = *(const bf16x8*)&kbuf[ln31 * 64 + ch];
      const bf16x8 kf1 = *(const bf16x8*)&kbuf[(32 + ln31) * 64 + ch];
      st0 = mfma32(kf0, qf[ks], st0);
      st1 = mfma32(kf1, qf[ks], st1);
    }
    const int q = R + ln31;
    float p0[16], p1[16];
#pragma unroll
    for (int r = 0; r < 16; ++r) {
      const int crow = (r & 3) + 8 * (r >> 2) + 4 * hf;
      float s0 = st0[r], s1 = st1[r];
      if (masked) {
        s0 = (kv0 + crow <= q) ? s0 : NEG_INF;
        s1 = (kv0 + 32 + crow <= q) ? s1 : NEG_INF;
      }
      p0[r] = __builtin_amdgcn_exp2f(s0);
      p1[r] = __builtin_amdgcn_exp2f(s1);
    }
    // repack P into PV A-frags: cvt_pk pairs + permlane32_swap
    bf16x8 pa[4];
#pragma unroll
    for (int mt = 0; mt < 2; ++mt) {
#pragma unroll
      for (int ksl = 0; ksl < 2; ++ksl) {
        const int bs = ksl * 8;
        uint32_t x0, y0, x1, y1;
        if (mt == 0) {
          x0 = pack2_bf16(p0[bs + 0], p0[bs + 1]);
          y0 = pack2_bf16(p0[bs + 4], p0[bs + 5]);
          x1 = pack2_bf16(p0[bs + 2], p0[bs + 3]);
          y1 = pack2_bf16(p0[bs + 6], p0[bs + 7]);
        } else {
          x0 = pack2_bf16(p1[bs + 0], p1[bs + 1]);
          y0 = pack2_bf16(p1[bs + 4], p1[bs + 5]);
          x1 = pack2_bf16(p1[bs + 2], p1[bs + 3]);
          y1 = pack2_bf16(p1[bs + 6], p1[bs + 7]);
        }
        asm volatile("v_permlane32_swap_b32 %0, %1" : "+v"(x0), "+v"(y0));
        asm volatile("v_permlane32_swap_b32 %0, %1" : "+v"(x1), "+v"(y1));
        union { uint32_t u[4]; bf16x8 v; } f;
        f.u[0] = x0; f.u[1] = x1; f.u[2] = y0; f.u[3] = y1;
        pa[mt * 2 + ksl] = f.v;
      }
    }
    // O += P.V ; l += P.ones
#pragma unroll
    for (int ks = 0; ks < 4; ++ks) {
      const int ch = (((2 * ks + hf) ^ (ln31 & 7)) * 8);
      const bf16x8 vf0 = *(const bf16x8*)&vbuf[ln31 * 64 + ch];
      const bf16x8 vf1 = *(const bf16x8*)&vbuf[(32 + ln31) * 64 + ch];
      accO0 = mfma32(pa[ks], vf0, accO0);
      accO1 = mfma32(pa[ks], vf1, accO1);
      accL  = mfma32(pa[ks], ones.v, accL);
    }
  };

  // two-round parity combine + writeout; scratch = consumed cur buffers
  auto combine_write = [&](int R, int cur) {
    float* scrA = (float*)&sK[cur][0][0];  // 16 KB
    float* scrB = (float*)&sV[cur][0][0];  // 16 KB
    const int base = (slice * 64 + lane) * 16;
    __builtin_amdgcn_s_barrier();          // all reads of pair done
    if (parity == 1) {
#pragma unroll
      for (int r = 0; r < 16; ++r) scrA[base + r] = accO0[r];
#pragma unroll
      for (int r = 0; r < 16; ++r) scrB[base + r] = accL[r];
    }
    __builtin_amdgcn_s_barrier();
    if (parity == 0) {
#pragma unroll
      for (int r = 0; r < 16; ++r) accO0[r] += scrA[base + r];
#pragma unroll
      for (int r = 0; r < 16; ++r) accL[r] += scrB[base + r];
    }
    __builtin_amdgcn_s_barrier();
    if (parity == 1) {
#pragma unroll
      for (int r = 0; r < 16; ++r) scrA[base + r] = accO1[r];
    }
    __builtin_amdgcn_s_barrier();
    if (parity == 0) {
#pragma unroll
      for (int r = 0; r < 16; ++r) accO1[r] += scrA[base + r];
      bf16* Ob = AO + (size_t)b * 2048 * 1024 + hd * 64;
#pragma unroll
      for (int r = 0; r < 16; ++r) {
        const int qr = R + (r & 3) + 8 * (r >> 2) + 4 * hf;
        const float inv = 1.0f / accL[r];
        Ob[(size_t)qr * 1024 + ln31]      = (bf16)(accO0[r] * inv);
        Ob[(size_t)qr * 1024 + 32 + ln31] = (bf16)(accO1[r] * inv);
      }
    }
    accO0 = f32x16{}; accO1 = f32x16{}; accL = f32x16{};
  };

  // ---- 17 identical pair-iterations per block, dbuf + counted vmcnt
  stage(0, 0);
  int cur = 0;
  for (int i = 0; i < 17; ++i) {
    if (i + 1 < 17) {
      const int nx = (i + 1 < n0) ? (i + 1) : (i + 1 - n0);
      stage(nx * 128, cur ^ 1);                         // next pair in flight
      asm volatile("s_waitcnt vmcnt(4)" ::: "memory");  // pair i landed
    } else {
      asm volatile("s_waitcnt vmcnt(0)" ::: "memory");  // final drain
    }
    __builtin_amdgcn_s_barrier();                       // pair i visible
    const bool inH = (i < n0);
    const int j = inH ? i : i - n0;
    const int R = inH ? RH : RL;
    const int kv0 = j * 128 + parity * 64;
    if (kv0 <= R + 31)                                  // wave-uniform
      body(&sK[cur][parity][0], &sV[cur][parity][0],
           inH ? qfH : qfL, kv0, R, kv0 + 63 > R);
    if (i == n0 - 1) combine_write(RH, cur);            // segment 0 done
    __builtin_amdgcn_s_barrier();                       // reads done
    cur ^= 1;
  }
  combine_write(RL, cur);
}

// ---------------------------------------------------------------- GEMM2: y = attn_out @ out_w^T
__global__ __launch_bounds__(256) void gemm_out_kernel(
    const bf16* __restrict__ A, const bf16* __restrict__ W,
    float* __restrict__ C) {
  constexpr int K = 1024;
  __shared__ __align__(16) bf16 sm[2 * 128 * 32];
  const int tid = threadIdx.x;
  const int w = tid >> 6, lane = tid & 63;
  const int m0 = blockIdx.x * 128, n0 = blockIdx.y * 128;
  const int wm = (w >> 1) * 64, wn = (w & 1) * 64;
  const int lrow = lane & 15, lk = (lane >> 4) * 8;
  f32x4 acc[4][4] = {};

  for (int k0 = 0; k0 < K; k0 += 32) {
#pragma unroll
    for (int i = 0; i < 4; ++i) {
      const int c = tid + 256 * i;
      const bf16* src = (c < 512)
          ? (A + (size_t)(m0 + (c >> 2)) * K + k0 + (c & 3) * 8)
          : (W + (size_t)(n0 + ((c - 512) >> 2)) * K + k0 + (c & 3) * 8);
      async16(src, sm + (w * 64 + i * 256) * 8);
    }
    __syncthreads();
    bf16x8 af[4], bfr[4];
#pragma unroll
    for (int mi = 0; mi < 4; ++mi)
      af[mi] = *(const bf16x8*)&sm[(wm + mi * 16 + lrow) * 32 + lk];
#pragma unroll
    for (int ni = 0; ni < 4; ++ni)
      bfr[ni] = *(const bf16x8*)&sm[128 * 32 + (wn + ni * 16 + lrow) * 32 + lk];
#pragma unroll
    for (int mi = 0; mi < 4; ++mi)
#pragma unroll
      for (int ni = 0; ni < 4; ++ni)
        acc[mi][ni] = mfma_bf16(af[mi], bfr[ni], acc[mi][ni]);
    __syncthreads();
  }

#pragma unroll
  for (int mi = 0; mi < 4; ++mi)
#pragma unroll
    for (int ni = 0; ni < 4; ++ni) {
      const int n = n0 + wn + ni * 16 + lrow;
#pragma unroll
      for (int r = 0; r < 4; ++r) {
        const int m = m0 + wm + mi * 16 + (lane >> 4) * 4 + r;
        C[(size_t)m * 1024 + n] = acc[mi][ni][r];
      }
    }
}

// ---------------------------------------------------------------- launch
extern "C" void kernel_launch(void* const* d_in, const int* in_sizes, int n_in,
                              void* d_out, int out_size, void* d_ws, size_t ws_size,
                              hipStream_t stream) {
  const float* x     = (const float*)d_in[0];
  const float* qkv_w = (const float*)d_in[1];
  const float* out_w = (const float*)d_in[2];
  float* out = (float*)d_out;

  char* ws = (char*)d_ws;
  bf16* xb    = (bf16*)(ws);                      // 8 MB  [4096][1024]
  bf16* aob   = (bf16*)(ws);                      // 8 MB  alias (xb dead after gemm_qkv)
  bf16* wqkvb = (bf16*)(ws + 8u * 1024 * 1024);   // 6 MB  [3072][1024]
  bf16* wob   = (bf16*)(ws + 14u * 1024 * 1024);  // 2 MB  [1024][1024]
  bf16* qkb   = (bf16*)(ws + 16u * 1024 * 1024);  // 16 MB [4096][2048]
  bf16* vtb   = (bf16*)(ws + 32u * 1024 * 1024);  // 8 MB  [32*64][2048]

  cast_all_kernel<<<8192, 256, 0, stream>>>(x, qkv_w, out_w, xb, wqkvb, wob);
  gemm_qkv_kernel<<<dim3(32, 24), 256, 0, stream>>>(xb, wqkvb, qkb, vtb);
  attn_kernel<<<dim3(256), 512, 0, stream>>>(qkb, vtb, aob);
  gemm_out_kernel<<<dim3(32, 8), 256, 0, stream>>>(aob, wob, out);
}

// Round 8
// 170.167 us; speedup vs baseline: 1.1520x; 1.0363x over previous
//
#include <hip/hip_runtime.h>
#include <hip/hip_bf16.h>
#include <stdint.h>

typedef __bf16 bf16;
typedef __attribute__((ext_vector_type(8))) __bf16 bf16x8;
typedef __attribute__((ext_vector_type(4))) __bf16 bf16x4;
typedef __attribute__((ext_vector_type(4))) float f32x4;

#define AS1 __attribute__((address_space(1)))
#define AS3 __attribute__((address_space(3)))

__device__ __forceinline__ void async16(const void* g, void* l) {
  __builtin_amdgcn_global_load_lds((AS1 uint32_t*)(g), (AS3 uint32_t*)(l), 16, 0, 0);
}

__device__ __forceinline__ f32x4 mfma_bf16(bf16x8 a, bf16x8 b, f32x4 c) {
  return __builtin_amdgcn_mfma_f32_16x16x32_bf16(a, b, c, 0, 0, 0);
}

__device__ __forceinline__ uint32_t pack2_bf16(float a, float b) {
  union { __hip_bfloat162 h2; uint32_t u; } u;
  u.h2 = __float22bfloat162_rn(float2{a, b});  // packed cvt: x=low, y=high
  return u.u;
}

// ---------------------------------------------------------------- fused casts
__global__ __launch_bounds__(256) void cast_all_kernel(
    const float* __restrict__ x, const float* __restrict__ w1,
    const float* __restrict__ w2, bf16* __restrict__ xb,
    bf16* __restrict__ w1b, bf16* __restrict__ w2b) {
  const int bid = blockIdx.x;
  const float* src;
  bf16* dst;
  int base;
  if (bid < 4096) { src = x;  dst = xb;  base = bid; }
  else if (bid < 7168) { src = w1; dst = w1b; base = bid - 4096; }
  else { src = w2; dst = w2b; base = bid - 7168; }
  const int i = (base * 256 + threadIdx.x) * 4;
  const float4 v = *(const float4*)(src + i);
  bf16x4 o;
  o[0] = (bf16)v.x; o[1] = (bf16)v.y; o[2] = (bf16)v.z; o[3] = (bf16)v.w;
  *(bf16x4*)(dst + i) = o;
}

// ---------------------------------------------------------------- GEMM1: qkv = x @ qkv_w^T
// R0-proven 128x128 structure.
__global__ __launch_bounds__(256) void gemm_qkv_kernel(
    const bf16* __restrict__ A, const bf16* __restrict__ W,
    bf16* __restrict__ QK, bf16* __restrict__ VT) {
  constexpr int K = 1024;
  __shared__ __align__(16) bf16 sm[2 * 128 * 32];
  const int tid = threadIdx.x;
  const int w = tid >> 6, lane = tid & 63;
  const int m0 = blockIdx.x * 128, n0 = blockIdx.y * 128;
  const int wm = (w >> 1) * 64, wn = (w & 1) * 64;
  const int lrow = lane & 15, quad = lane >> 4;
  const int lk = quad * 8;
  f32x4 acc[4][4] = {};

  for (int k0 = 0; k0 < K; k0 += 32) {
#pragma unroll
    for (int i = 0; i < 4; ++i) {
      const int c = tid + 256 * i;
      const bf16* src = (c < 512)
          ? (A + (size_t)(m0 + (c >> 2)) * K + k0 + (c & 3) * 8)
          : (W + (size_t)(n0 + ((c - 512) >> 2)) * K + k0 + (c & 3) * 8);
      async16(src, sm + (w * 64 + i * 256) * 8);
    }
    __syncthreads();
    bf16x8 af[4], bfr[4];
#pragma unroll
    for (int mi = 0; mi < 4; ++mi)
      af[mi] = *(const bf16x8*)&sm[(wm + mi * 16 + lrow) * 32 + lk];
#pragma unroll
    for (int ni = 0; ni < 4; ++ni)
      bfr[ni] = *(const bf16x8*)&sm[128 * 32 + (wn + ni * 16 + lrow) * 32 + lk];
#pragma unroll
    for (int mi = 0; mi < 4; ++mi)
#pragma unroll
      for (int ni = 0; ni < 4; ++ni)
        acc[mi][ni] = mfma_bf16(af[mi], bfr[ni], acc[mi][ni]);
    __syncthreads();
  }

  // ---- epilogue: LDS transpose -> coalesced 16B global stores
  bf16* s2 = sm;  // [64][128]
  const bool isV = (n0 >= 2048);
  const int bb = m0 >> 11;
  const int mt = m0 & 2047;
  if (!isV) {
#pragma unroll
    for (int c = 0; c < 2; ++c) {
      if ((w >> 1) == c) {
#pragma unroll
        for (int mi = 0; mi < 4; ++mi)
#pragma unroll
          for (int ni = 0; ni < 4; ++ni) {
            const int nr = wn + ni * 16 + lrow;
#pragma unroll
            for (int r = 0; r < 4; ++r)
              s2[(mi * 16 + quad * 4 + r) * 128 + nr] = (bf16)acc[mi][ni][r];
          }
      }
      __syncthreads();
#pragma unroll
      for (int p = 0; p < 4; ++p) {
        const int row = p * 16 + (tid >> 4);
        const int colc = (tid & 15) * 8;
        const bf16x8 v = *(const bf16x8*)&s2[row * 128 + colc];
        *(bf16x8*)(QK + (size_t)(m0 + c * 64 + row) * 2048 + n0 + colc) = v;
      }
      __syncthreads();
    }
  } else {
#pragma unroll
    for (int c = 0; c < 2; ++c) {
      if ((w & 1) == c) {
#pragma unroll
        for (int mi = 0; mi < 4; ++mi)
#pragma unroll
          for (int ni = 0; ni < 4; ++ni) {
            const int nl = ni * 16 + lrow;
            bf16x4 pk4;
#pragma unroll
            for (int r = 0; r < 4; ++r) pk4[r] = (bf16)acc[mi][ni][r];
            *(bf16x4*)&s2[nl * 128 + wm + mi * 16 + quad * 4] = pk4;
          }
      }
      __syncthreads();
#pragma unroll
      for (int p = 0; p < 4; ++p) {
        const int row = p * 16 + (tid >> 4);
        const int colc = (tid & 15) * 8;
        const bf16x8 v = *(const bf16x8*)&s2[row * 128 + colc];
        const int vtrow = bb * 1024 + (n0 - 2048) + c * 64 + row;
        *(bf16x8*)(VT + (size_t)vtrow * 2048 + mt + colc) = v;
      }
      __syncthreads();
    }
  }
}

// ---------------------------------------------------------------- attention (flash, causal)
// R14: break barrier-lockstep serialization. Evidence across R6-R13: pipe-busy
// fractions SUM to ~83% (MFMA 17 + VALU 32 + LDS ~25 + stage ~8) -> pipes used
// serially by one lockstep wave-group per CU; every schedule tweak inside the
// group was null. Fix: 2 independent 4-wave blocks per CU (grid 512 = 32bh x
// 8bp x 2sub, 64 KB LDS/block -> 2 blocks/CU), each with its own barriers ->
// cross-block pipe overlap. Block = 64 q-rows (wave = 16 rows, proven R11
// 16x16 body), balanced triangle: segment H (band 15-bp) then L (band bp) =
// 17 pair-iters for EVERY block. Wave does both 64-kv tiles of each staged
// pair into one accumulator (no parity combine). Dbuf pair + counted vmcnt(8).
__global__ __launch_bounds__(256) void attn_kernel(
    const bf16* __restrict__ QK, const bf16* __restrict__ VT,
    bf16* __restrict__ AO) {
  __shared__ __align__(16) bf16 sK[2][2][64 * 64];  // [buf][tile]: 32 KB
  __shared__ __align__(16) bf16 sV[2][2][64 * 64];  // [buf][tile]: 32 KB
  const int bid = blockIdx.x;
  const int bh = bid & 31;          // bid&7 == bh&7 -> XCD-local heads
  const int bp = (bid >> 5) & 7;    // band-pair index
  const int sub = bid >> 8;         // which 64-row half of the band
  const int b = bh >> 4, hd = bh & 15;
  const int tid = threadIdx.x, w = tid >> 6, lane = tid & 63;
  const int col = lane & 15, quad = lane >> 4;
  const bf16* Qb = QK + (size_t)b * 2048 * 2048 + hd * 64;
  const bf16* Kb = Qb + 1024;
  const bf16* Vb = VT + (size_t)bh * 64 * 2048;
  const float NEG_INF = -__builtin_inff();
  constexpr float QSCALE = 0.18033688011112042f;  // 0.125 * log2(e)
  const int n0 = 16 - bp;                         // segment-H pair count

  // ones A-frag for l accumulation (bf16 1.0 = 0x3F80)
  union { uint32_t u[4]; bf16x8 v; } ones;
  ones.u[0] = 0x3F803F80u; ones.u[1] = 0x3F803F80u;
  ones.u[2] = 0x3F803F80u; ones.u[3] = 0x3F803F80u;

  // wave's 16 q-rows per segment; Q B-frags in registers, pre-scaled
  const int RA = (15 - bp) * 128 + sub * 64 + w * 16;  // segment H
  const int RB = bp * 128 + sub * 64 + w * 16;         // segment L
  const int qrowA = RA + col, qrowB = RB + col;
  bf16x8 qfA[2], qfB[2];
#pragma unroll
  for (int kk = 0; kk < 2; ++kk) {
    bf16x8 v0 = *(const bf16x8*)(Qb + (size_t)qrowA * 2048 + kk * 32 + quad * 8);
    bf16x8 v1 = *(const bf16x8*)(Qb + (size_t)qrowB * 2048 + kk * 32 + quad * 8);
#pragma unroll
    for (int e = 0; e < 8; ++e) {
      v0[e] = (bf16)((float)v0[e] * QSCALE);
      v1[e] = (bf16)((float)v1[e] * QSCALE);
    }
    qfA[kk] = v0; qfB[kk] = v1;
  }

  // stage a pair of kv tiles into buffer c: K rows [s0,s0+128), V^T cols same
  // 256 threads x 8 async16 each (chunk-XOR swizzle on the global source)
  auto stage = [&](int s0, int c) {
    bf16* dK = &sK[c][0][0];
    bf16* dV = &sV[c][0][0];
#pragma unroll
    for (int i2 = 0; i2 < 4; ++i2) {
      const int L = tid + 256 * i2;         // 0..1023 chunks of 16B
      const int buf = L >> 9, Lr = L & 511;
      const int row = Lr >> 3;
      const int ch = (Lr & 7) ^ (row & 7);
      async16(Kb + (size_t)(s0 + buf * 64 + row) * 2048 + ch * 8, dK + L * 8);
    }
#pragma unroll
    for (int i2 = 0; i2 < 4; ++i2) {
      const int L = tid + 256 * i2;
      const int buf = L >> 9, Lr = L & 511;
      const int d = Lr >> 3;
      const int ch = (Lr & 7) ^ (d & 7);
      async16(Vb + (size_t)d * 2048 + s0 + buf * 64 + ch * 8, dV + L * 8);
    }
  };

  // sigma-mapped K rows: srow(m) = 32*(m&1) + quad*8 + 4*(m>>1) + (col&3)
  int srow[4];
#pragma unroll
  for (int m = 0; m < 4; ++m)
    srow[m] = 32 * (m & 1) + (col >> 2) * 8 + 4 * (m >> 1) + (col & 3);

  f32x4 accO[4] = {};   // O^T partial per dtile (wave's 16 q-rows)
  f32x4 accL = {};      // l partial via ones-MFMA (all rows equal)

  // one 64-kv tile body for this wave's 16 q-rows
  auto body = [&](const bf16* kbuf, const bf16* vbuf, const bf16x8* qf,
                  int kv0, int qrowv, bool masked) {
    f32x4 st[4] = {};
#pragma unroll
    for (int kk = 0; kk < 2; ++kk) {
      bf16x8 kf[4];
#pragma unroll
      for (int m = 0; m < 4; ++m)
        kf[m] = *(const bf16x8*)&kbuf[srow[m] * 64 + (((kk * 4 + quad) ^ (srow[m] & 7)) * 8)];
      __builtin_amdgcn_s_setprio(1);
#pragma unroll
      for (int m = 0; m < 4; ++m)
        st[m] = mfma_bf16(kf[m], qf[kk], st[m]);
      __builtin_amdgcn_s_setprio(0);
    }

    if (masked) {
#pragma unroll
      for (int m = 0; m < 4; ++m) {
        const int kvb = kv0 + 32 * (m & 1) + quad * 8 + 4 * (m >> 1);
#pragma unroll
        for (int r = 0; r < 4; ++r)
          st[m][r] = (kvb + r <= qrowv) ? st[m][r] : NEG_INF;
      }
    }

    // p = exp2(st): packed bf16 cvt, no offset, no row-sum VALU
    uint32_t pk[4][2];
#pragma unroll
    for (int m = 0; m < 4; ++m) {
      const float p0 = __builtin_amdgcn_exp2f(st[m][0]);
      const float p1 = __builtin_amdgcn_exp2f(st[m][1]);
      const float p2 = __builtin_amdgcn_exp2f(st[m][2]);
      const float p3 = __builtin_amdgcn_exp2f(st[m][3]);
      pk[m][0] = pack2_bf16(p0, p1);
      pk[m][1] = pack2_bf16(p2, p3);
    }

    // O^T += V^T . P^T ; l += ones . P^T
#pragma unroll
    for (int kk = 0; kk < 2; ++kk) {
      bf16x8 vf[4];
#pragma unroll
      for (int d = 0; d < 4; ++d) {
        const int row = d * 16 + col;
        vf[d] = *(const bf16x8*)&vbuf[row * 64 + (((kk * 4 + quad) ^ (row & 7)) * 8)];
      }
      union { uint32_t u[4]; bf16x8 v; } f;
      f.u[0] = pk[kk][0];
      f.u[1] = pk[kk][1];
      f.u[2] = pk[2 + kk][0];
      f.u[3] = pk[2 + kk][1];
      __builtin_amdgcn_s_setprio(1);
      accL = mfma_bf16(ones.v, f.v, accL);
#pragma unroll
      for (int d = 0; d < 4; ++d)
        accO[d] = mfma_bf16(vf[d], f.v, accO[d]);
      __builtin_amdgcn_s_setprio(0);
    }
  };

  auto writeout = [&](int qrowv) {
    bf16* Ob = AO + (size_t)b * 2048 * 1024 + hd * 64;
    const float inv = 1.0f / accL[0];  // lane's l (ones-MFMA rows all equal)
#pragma unroll
    for (int d = 0; d < 4; ++d) {
      bf16x4 o;
#pragma unroll
      for (int r = 0; r < 4; ++r) o[r] = (bf16)(accO[d][r] * inv);
      *(bf16x4*)(Ob + (size_t)qrowv * 1024 + d * 16 + quad * 4) = o;
    }
  };

  // ---- 17 identical pair-iterations per block, dbuf + counted vmcnt
  stage(0, 0);
  int cur = 0;
  for (int i = 0; i < 17; ++i) {
    if (i + 1 < 17) {
      const int nx = (i + 1 < n0) ? (i + 1) : (i + 1 - n0);
      stage(nx * 128, cur ^ 1);                         // next pair in flight
      asm volatile("s_waitcnt vmcnt(8)" ::: "memory");  // pair i landed
    } else {
      asm volatile("s_waitcnt vmcnt(0)" ::: "memory");  // final drain
    }
    __builtin_amdgcn_s_barrier();                       // pair i visible
    const bool inH = (i < n0);
    const int j = inH ? i : i - n0;
    const int Rw = inH ? RA : RB;
    const int qrowv = inH ? qrowA : qrowB;
    const bf16x8* qf = inH ? qfA : qfB;
    const int kv0 = j * 128;
    if (kv0 <= Rw + 15)                                 // wave-uniform
      body(&sK[cur][0][0], &sV[cur][0][0], qf, kv0, qrowv, kv0 + 63 > Rw);
    if (kv0 + 64 <= Rw + 15)
      body(&sK[cur][1][0], &sV[cur][1][0], qf, kv0 + 64, qrowv, kv0 + 127 > Rw);
    if (i == n0 - 1) {                                  // segment H done
      writeout(qrowA);
#pragma unroll
      for (int d = 0; d < 4; ++d) accO[d] = f32x4{0.f, 0.f, 0.f, 0.f};
      accL = f32x4{0.f, 0.f, 0.f, 0.f};
    }
    __builtin_amdgcn_s_barrier();                       // reads done
    cur ^= 1;
  }
  writeout(qrowB);
}

// ---------------------------------------------------------------- GEMM2: y = attn_out @ out_w^T
__global__ __launch_bounds__(256) void gemm_out_kernel(
    const bf16* __restrict__ A, const bf16* __restrict__ W,
    float* __restrict__ C) {
  constexpr int K = 1024;
  __shared__ __align__(16) bf16 sm[2 * 128 * 32];
  const int tid = threadIdx.x;
  const int w = tid >> 6, lane = tid & 63;
  const int m0 = blockIdx.x * 128, n0 = blockIdx.y * 128;
  const int wm = (w >> 1) * 64, wn = (w & 1) * 64;
  const int lrow = lane & 15, lk = (lane >> 4) * 8;
  f32x4 acc[4][4] = {};

  for (int k0 = 0; k0 < K; k0 += 32) {
#pragma unroll
    for (int i = 0; i < 4; ++i) {
      const int c = tid + 256 * i;
      const bf16* src = (c < 512)
          ? (A + (size_t)(m0 + (c >> 2)) * K + k0 + (c & 3) * 8)
          : (W + (size_t)(n0 + ((c - 512) >> 2)) * K + k0 + (c & 3) * 8);
      async16(src, sm + (w * 64 + i * 256) * 8);
    }
    __syncthreads();
    bf16x8 af[4], bfr[4];
#pragma unroll
    for (int mi = 0; mi < 4; ++mi)
      af[mi] = *(const bf16x8*)&sm[(wm + mi * 16 + lrow) * 32 + lk];
#pragma unroll
    for (int ni = 0; ni < 4; ++ni)
      bfr[ni] = *(const bf16x8*)&sm[128 * 32 + (wn + ni * 16 + lrow) * 32 + lk];
#pragma unroll
    for (int mi = 0; mi < 4; ++mi)
#pragma unroll
      for (int ni = 0; ni < 4; ++ni)
        acc[mi][ni] = mfma_bf16(af[mi], bfr[ni], acc[mi][ni]);
    __syncthreads();
  }

#pragma unroll
  for (int mi = 0; mi < 4; ++mi)
#pragma unroll
    for (int ni = 0; ni < 4; ++ni) {
      const int n = n0 + wn + ni * 16 + lrow;
#pragma unroll
      for (int r = 0; r < 4; ++r) {
        const int m = m0 + wm + mi * 16 + (lane >> 4) * 4 + r;
        C[(size_t)m * 1024 + n] = acc[mi][ni][r];
      }
    }
}

// ---------------------------------------------------------------- launch
extern "C" void kernel_launch(void* const* d_in, const int* in_sizes, int n_in,
                              void* d_out, int out_size, void* d_ws, size_t ws_size,
                              hipStream_t stream) {
  const float* x     = (const float*)d_in[0];
  const float* qkv_w = (const float*)d_in[1];
  const float* out_w = (const float*)d_in[2];
  float* out = (float*)d_out;

  char* ws = (char*)d_ws;
  bf16* xb    = (bf16*)(ws);                      // 8 MB  [4096][1024]
  bf16* aob   = (bf16*)(ws);                      // 8 MB  alias (xb dead after gemm_qkv)
  bf16* wqkvb = (bf16*)(ws + 8u * 1024 * 1024);   // 6 MB  [3072][1024]
  bf16* wob   = (bf16*)(ws + 14u * 1024 * 1024);  // 2 MB  [1024][1024]
  bf16* qkb   = (bf16*)(ws + 16u * 1024 * 1024);  // 16 MB [4096][2048]
  bf16* vtb   = (bf16*)(ws + 32u * 1024 * 1024);  // 8 MB  [32*64][2048]

  cast_all_kernel<<<8192, 256, 0, stream>>>(x, qkv_w, out_w, xb, wqkvb, wob);
  gemm_qkv_kernel<<<dim3(32, 24), 256, 0, stream>>>(xb, wqkvb, qkb, vtb);
  attn_kernel<<<dim3(512), 256, 0, stream>>>(qkb, vtb, aob);
  gemm_out_kernel<<<dim3(32, 8), 256, 0, stream>>>(aob, wob, out);
}